// Round 12
// baseline (327.905 us; speedup 1.0000x reference)
//
#include <hip/hip_runtime.h>

typedef __bf16 bf16;
typedef __bf16 bf16x8 __attribute__((ext_vector_type(8)));
typedef float f32x4 __attribute__((ext_vector_type(4)));

__device__ __forceinline__ f32x4 mfma16(bf16x8 a, bf16x8 b, f32x4 c) {
  return __builtin_amdgcn_mfma_f32_16x16x32_bf16(a, b, c, 0, 0, 0);
}
__device__ __forceinline__ void gload16(const bf16* g, bf16* l) {
  __builtin_amdgcn_global_load_lds((const __attribute__((address_space(1))) unsigned int*)g,
                                   (__attribute__((address_space(3))) unsigned int*)l, 16, 0, 0);
}

// ---------------- convert x f32 -> bf16 (linear) ----------------
__global__ __launch_bounds__(256) void cvt_x_kernel(const float* __restrict__ in,
                                                    bf16* __restrict__ out, int n8) {
  int i = blockIdx.x * 256 + threadIdx.x;
  if (i >= n8) return;
  const float4* p = (const float4*)in + (size_t)i * 2;
  float4 f0 = p[0], f1 = p[1];
  bf16x8 o;
  o[0] = (bf16)f0.x; o[1] = (bf16)f0.y; o[2] = (bf16)f0.z; o[3] = (bf16)f0.w;
  o[4] = (bf16)f1.x; o[5] = (bf16)f1.y; o[6] = (bf16)f1.z; o[7] = (bf16)f1.w;
  *((bf16x8*)out + i) = o;
}

// ------- fused: 4x weight transpose-convert + bias fuse (grid 1036) -------
__global__ __launch_bounds__(256) void cvt_wtb_kernel(
    const float* __restrict__ wq, const float* __restrict__ wk,
    const float* __restrict__ wv, const float* __restrict__ wo,
    const float* __restrict__ bq, const float* __restrict__ bk,
    const float* __restrict__ bv, bf16* __restrict__ wqkvt,
    bf16* __restrict__ wot, float* __restrict__ bqkv) {
  int blk = blockIdx.x;
  int tid = threadIdx.x;
  if (blk >= 1024) {
    int i = (blk - 1024) * 256 + tid;
    if (i < 1024) bqkv[i] = bq[i];
    else if (i < 2048) bqkv[i] = bk[i - 1024];
    else if (i < 3072) bqkv[i] = bv[i - 2048];
    return;
  }
  __shared__ float t[64][68];
  int wsel = blk >> 8, sub = blk & 255;
  const float* in = wsel == 0 ? wq : wsel == 1 ? wk : wsel == 2 ? wv : wo;
  bf16* out = (wsel == 3) ? wot : (wqkvt + (size_t)wsel * (1u << 20));
  int bx = sub & 15;
  int by = sub >> 4;
  int r = tid >> 2, p = tid & 3;
  const float* src = in + (size_t)(by * 64 + r) * 1024 + bx * 64 + p * 16;
#pragma unroll
  for (int j = 0; j < 16; j += 4)
    *(float4*)&t[r][p * 16 + j] = *(const float4*)(src + j);
  __syncthreads();
  int n = tid >> 2, sp = tid & 3;
  bf16 tmp[16];
#pragma unroll
  for (int j = 0; j < 16; ++j) tmp[j] = (bf16)t[sp * 16 + j][n];
  bf16* dst = out + (size_t)(bx * 64 + n) * 1024 + by * 64 + sp * 16;
  *(bf16x8*)dst = *(bf16x8*)&tmp[0];
  *(bf16x8*)(dst + 8) = *(bf16x8*)&tmp[8];
}

// ---------------- parallel deterministic stable sort of lag by rank ----------------
__global__ __launch_bounds__(256) void sort_lag_kernel(const int* __restrict__ lag,
                                                       int* __restrict__ perm,
                                                       int* __restrict__ slag) {
  __shared__ int l[2048];
  int tid = threadIdx.x;
  for (int i = tid; i < 2048; i += 256) l[i] = lag[i];
  __syncthreads();
  int i = blockIdx.x * 32 + (tid >> 3);
  int s = tid & 7;
  int vi = l[i];
  int cnt = 0;
  for (int j = s * 256; j < s * 256 + 256; j += 4) {
    int4 vj = *(const int4*)&l[j];
    cnt += (vj.x < vi || (vj.x == vi && (j + 0) < i));
    cnt += (vj.y < vi || (vj.y == vi && (j + 1) < i));
    cnt += (vj.z < vi || (vj.z == vi && (j + 2) < i));
    cnt += (vj.w < vi || (vj.w == vi && (j + 3) < i));
  }
  cnt += __shfl_xor(cnt, 1);
  cnt += __shfl_xor(cnt, 2);
  cnt += __shfl_xor(cnt, 4);
  if (s == 0) { perm[cnt] = i; slag[cnt] = vi; }
}

// ---- pack K rows sorted (kp[(b*16+h)*2048+ss][64]) + V transpose sorted (vt[bh][d][ss]) ----
__global__ __launch_bounds__(256) void pack_kv_kernel(const bf16* __restrict__ qkv,
                                                      const int* __restrict__ perm,
                                                      bf16* __restrict__ kp,
                                                      bf16* __restrict__ vt) {
  __shared__ bf16 t[64][72];
  int blk = blockIdx.x;
  int st = blk & 31, h = (blk >> 5) & 15, b = blk >> 9;
  int tid = threadIdx.x;
  int r = tid >> 2, p = tid & 3;
  int src_s = perm[st * 64 + r];
  {
    const bf16* src = qkv + (size_t)(b * 2048 + src_s) * 3072 + 1024 + h * 64 + p * 16;
    bf16* dst = kp + (size_t)((b * 16 + h) * 2048 + st * 64 + r) * 64 + p * 16;
    *(bf16x8*)dst = *(const bf16x8*)src;
    *(bf16x8*)(dst + 8) = *(const bf16x8*)(src + 8);
  }
  {
    const bf16* src = qkv + (size_t)(b * 2048 + src_s) * 3072 + 2048 + h * 64 + p * 16;
    *(bf16x8*)&t[r][p * 16] = *(const bf16x8*)src;
    *(bf16x8*)&t[r][p * 16 + 8] = *(const bf16x8*)(src + 8);
    __syncthreads();
    int d = tid >> 2, sp = tid & 3;
    bf16 tmp[16];
#pragma unroll
    for (int j = 0; j < 16; ++j) tmp[j] = t[sp * 16 + j][d];
    bf16* dst = vt + (size_t)((b * 16 + h) * 64 + d) * 2048 + st * 64 + sp * 16;
    *(bf16x8*)dst = *(bf16x8*)&tmp[0];
    *(bf16x8*)(dst + 8) = *(bf16x8*)&tmp[8];
  }
}

// ---------------- bf16 GEMM: C[M][N] = A[M][K] * Bt[N][K]^T + bias, optional col-scale ----------------
template <int OUT_BF16>
__global__ __launch_bounds__(256) void gemm_bt_kernel(
    const bf16* __restrict__ A, const bf16* __restrict__ Bt,
    const float* __restrict__ bias, void* __restrict__ C,
    int M, int N, int K, int scale_cols, float scale_val) {
  __shared__ __align__(16) bf16 As[128 * 64];
  __shared__ __align__(16) bf16 Bs[128 * 64];
  int bn = blockIdx.x * 128, bm = blockIdx.y * 128;
  int tid = threadIdx.x;
  int l = tid & 63;
  int w = tid >> 6;
  int wr = w >> 1, wc = w & 1;
  int g = l >> 4, c = l & 15;
  int swz = (c & 7) << 3;
  int srow = l >> 3;
  int scol = ((l & 7) ^ srow) << 3;
  const bf16* Ap = A + (size_t)(bm + w * 32 + srow) * K + scol;
  const bf16* Bp = Bt + (size_t)(bn + w * 32 + srow) * K + scol;
  bf16* AsW = As + w * 32 * 64;
  bf16* BsW = Bs + w * 32 * 64;

  f32x4 acc[4][4] = {};
  for (int k0 = 0; k0 < K; k0 += 64) {
    __syncthreads();
#pragma unroll
    for (int i = 0; i < 4; ++i) {
      gload16(Ap + (size_t)(8 * i) * K + k0, AsW + i * 512);
      gload16(Bp + (size_t)(8 * i) * K + k0, BsW + i * 512);
    }
    __syncthreads();
#pragma unroll
    for (int kh = 0; kh < 2; ++kh) {
      bf16x8 af[4], bfr[4];
#pragma unroll
      for (int m = 0; m < 4; ++m)
        af[m] = *(const bf16x8*)&As[(wr * 64 + m * 16 + c) * 64 + ((kh * 32 + g * 8) ^ swz)];
#pragma unroll
      for (int n = 0; n < 4; ++n)
        bfr[n] = *(const bf16x8*)&Bs[(wc * 64 + n * 16 + c) * 64 + ((kh * 32 + g * 8) ^ swz)];
#pragma unroll
      for (int m = 0; m < 4; ++m)
#pragma unroll
        for (int n = 0; n < 4; ++n)
          acc[m][n] = mfma16(af[m], bfr[n], acc[m][n]);
    }
  }
  int rowb = bm + wr * 64;
  int colb = bn + wc * 64;
#pragma unroll
  for (int n = 0; n < 4; ++n) {
    int col = colb + n * 16 + c;
    float bv = bias[col];
    float s = (col < scale_cols) ? scale_val : 1.0f;
#pragma unroll
    for (int m = 0; m < 4; ++m) {
      int row = rowb + m * 16 + g * 4;
#pragma unroll
      for (int j = 0; j < 4; ++j) {
        float v = (acc[m][n][j] + bv) * s;
        if (OUT_BF16)
          ((bf16*)C)[(size_t)(row + j) * N + col] = (bf16)v;
        else
          ((float*)C)[(size_t)(row + j) * N + col] = v;
      }
    }
  }
}

// ---------------- flash attention, barrier-free: K/V fragments direct from L1/L2 ----------------
// grid 1024 = qt32 x h16 x b2 (XCD-swizzled); 4 waves x 16 q; KVBLK=64, 32 tiles.
// No K/V LDS staging: K tile (8KB, kp contiguous) and V tile (8KB, vt rows) are L1-resident;
// fragments load straight from global with const-offset addressing (the pre-swizzle logical
// indices validated in R2). Zero barriers in the K-loop (Ps is per-wave) -> free-running
// waves, 4 blocks/CU. LDS: Ps 9.2KB + bias_s 2.1KB only. lagk from slag (coalesced VMEM).
__global__ __launch_bounds__(256, 4) void attn_kernel(
    const bf16* __restrict__ qkv, const bf16* __restrict__ kp,
    const bf16* __restrict__ vt, const int* __restrict__ lag,
    const int* __restrict__ slag, const float* __restrict__ lag_bias,
    bf16* __restrict__ out) {
  __shared__ __align__(16) bf16 Ps[4][16][72];
  __shared__ float bias_s[516];

  int blk = blockIdx.x;
  blk = (blk & 7) * 128 + (blk >> 3);  // bijective XCD swizzle (1024 % 8 == 0)
  int qt = blk & 31;
  int h = (blk >> 5) & 15;
  int b = blk >> 9;
  int tid = threadIdx.x;
  int w = tid >> 6, l = tid & 63, g = l >> 4, c = l & 15;

  for (int i = tid; i < 513; i += 256) bias_s[i] = lag_bias[h * 513 + i] * 1.44269504f;

  int q0 = qt * 64 + w * 16;
  const bf16* qbase = qkv + (size_t)(b * 2048 + q0) * 3072 + h * 64;
  bf16x8 qf[2];
  qf[0] = *(const bf16x8*)(qbase + (size_t)c * 3072 + g * 8);
  qf[1] = *(const bf16x8*)(qbase + (size_t)c * 3072 + 32 + g * 8);

  int lagq[4];
#pragma unroll
  for (int j = 0; j < 4; ++j) lagq[j] = lag[q0 + g * 4 + j];

  // per-lane fragment base pointers (const offsets inside the loop)
  const bf16* krow = kp + (size_t)(b * 16 + h) * 2048 * 64 + (size_t)c * 64 + g * 8;
  const bf16* vrow[4];
#pragma unroll
  for (int n = 0; n < 4; ++n)
    vrow[n] = vt + (size_t)((b * 16 + h) * 64 + n * 16 + c) * 2048 + g * 8;
  const int* lagp = slag + c;

  __syncthreads();  // bias_s ready (only barrier besides this in the kernel)

  f32x4 oacc[4] = {};
  float psum[4] = {0.f, 0.f, 0.f, 0.f};

  for (int kt = 0; kt < 2048; kt += 64) {
    // lagk: coalesced loads from sorted lag
    int lagk[4];
#pragma unroll
    for (int kb = 0; kb < 4; ++kb) lagk[kb] = lagp[kt + kb * 16];

    // QK^T: S[q=g*4+j][key=kb*16+c]; K fragments direct from global (L1-hot)
    f32x4 sf[4] = {};
    const bf16* kt_base = krow + (size_t)kt * 64;
#pragma unroll
    for (int kb = 0; kb < 4; ++kb) {
      bf16x8 k0 = *(const bf16x8*)(kt_base + kb * 1024);
      bf16x8 k1 = *(const bf16x8*)(kt_base + kb * 1024 + 32);
      sf[kb] = mfma16(qf[0], k0, sf[kb]);
      sf[kb] = mfma16(qf[1], k1, sf[kb]);
    }

    // no-max softmax: p = exp2(s + bias), bias gathered from LDS (sorted keys => ~broadcast)
#pragma unroll
    for (int kb = 0; kb < 4; ++kb) {
#pragma unroll
      for (int j = 0; j < 4; ++j) {
        int ld = lagq[j] - lagk[kb];
        ld = ld < 0 ? -ld : ld;
        float p = __builtin_amdgcn_exp2f(sf[kb][j] + bias_s[ld]);
        psum[j] += p;
        Ps[w][g * 4 + j][kb * 16 + c] = (bf16)p;
      }
    }
    asm volatile("s_waitcnt lgkmcnt(0)" ::: "memory");
    bf16x8 pa0 = *(const bf16x8*)&Ps[w][c][g * 8];
    bf16x8 pa1 = *(const bf16x8*)&Ps[w][c][32 + g * 8];
    // PV: V^T fragments direct from global (L1-hot rows)
#pragma unroll
    for (int n = 0; n < 4; ++n) {
      bf16x8 v0 = *(const bf16x8*)(vrow[n] + kt);
      bf16x8 v1 = *(const bf16x8*)(vrow[n] + kt + 32);
      oacc[n] = mfma16(pa0, v0, oacc[n]);
      oacc[n] = mfma16(pa1, v1, oacc[n]);
    }
  }

  // one-time row-sum reduction across the 16 c-lanes, then normalize+store
#pragma unroll
  for (int j = 0; j < 4; ++j) {
    float s = psum[j];
    s += __shfl_xor(s, 1);
    s += __shfl_xor(s, 2);
    s += __shfl_xor(s, 4);
    s += __shfl_xor(s, 8);
    float inv = 1.f / s;
    bf16* ob = out + (size_t)(b * 2048 + q0 + g * 4 + j) * 1024 + h * 64;
#pragma unroll
    for (int n = 0; n < 4; ++n)
      ob[n * 16 + c] = (bf16)(oacc[n][j] * inv);
  }
}

extern "C" void kernel_launch(void* const* d_in, const int* in_sizes, int n_in,
                              void* d_out, int out_size, void* d_ws, size_t ws_size,
                              hipStream_t stream) {
  const float* x        = (const float*)d_in[0];
  const int*   lag      = (const int*)d_in[1];
  const float* wq       = (const float*)d_in[2];
  const float* bq       = (const float*)d_in[3];
  const float* wk       = (const float*)d_in[4];
  const float* bk       = (const float*)d_in[5];
  const float* wv       = (const float*)d_in[6];
  const float* bv       = (const float*)d_in[7];
  const float* wo       = (const float*)d_in[8];
  const float* bo       = (const float*)d_in[9];
  const float* lag_bias = (const float*)d_in[10];

  char* ws = (char*)d_ws;
  bf16*  xb    = (bf16*)ws;                        // 8 MB (x bf16; reused as kp after QKV GEMM)
  bf16*  wqkvt = (bf16*)(ws + (8u  << 20));        // 6 MB
  bf16*  wot   = (bf16*)(ws + (14u << 20));        // 2 MB
  float* bqkv  = (float*)(ws + (16u << 20));       // 12 KB
  int*   perm  = (int*)(ws + (16u << 20) + 32768); // 8 KB
  int*   slag  = (int*)(ws + (16u << 20) + 65536); // 8 KB
  bf16*  qkv   = (bf16*)(ws + (17u << 20));        // 24 MB
  bf16*  vtb   = (bf16*)(ws + (41u << 20));        // 8 MB
  bf16*  aout  = (bf16*)(ws + (49u << 20));        // 8 MB
  bf16*  kpk   = xb;                               // packed sorted K (xb dead after GEMM)

  sort_lag_kernel<<<64, 256, 0, stream>>>(lag, perm, slag);
  cvt_x_kernel<<<2048, 256, 0, stream>>>(x, xb, 524288);
  cvt_wtb_kernel<<<1036, 256, 0, stream>>>(wq, wk, wv, wo, bq, bk, bv, wqkvt, wot, bqkv);
  gemm_bt_kernel<1><<<dim3(24, 32), 256, 0, stream>>>(
      xb, wqkvt, bqkv, qkv, 4096, 3072, 1024, 1024, 0.125f * 1.44269504f);
  pack_kv_kernel<<<1024, 256, 0, stream>>>(qkv, perm, kpk, vtb);
  attn_kernel<<<1024, 256, 0, stream>>>(qkv, kpk, vtb, lag, slag, lag_bias, aout);
  gemm_bt_kernel<0><<<dim3(8, 32), 256, 0, stream>>>(
      aout, wot, bo, (float*)d_out, 4096, 1024, 1024, 0, 1.0f);
}

// Round 13
// 179.027 us; speedup vs baseline: 1.8316x; 1.8316x over previous
//
#include <hip/hip_runtime.h>

typedef __bf16 bf16;
typedef __bf16 bf16x8 __attribute__((ext_vector_type(8)));
typedef float f32x4 __attribute__((ext_vector_type(4)));

__device__ __forceinline__ f32x4 mfma16(bf16x8 a, bf16x8 b, f32x4 c) {
  return __builtin_amdgcn_mfma_f32_16x16x32_bf16(a, b, c, 0, 0, 0);
}
__device__ __forceinline__ void gload16(const bf16* g, bf16* l) {
  __builtin_amdgcn_global_load_lds((const __attribute__((address_space(1))) unsigned int*)g,
                                   (__attribute__((address_space(3))) unsigned int*)l, 16, 0, 0);
}

// ------- fused prep: x f32->bf16 (blocks 0..2047), 4x weight transpose (2048..3071),
//         bias concat (3072..3083). grid 3084 -------
__global__ __launch_bounds__(256) void prep_kernel(
    const float* __restrict__ x, const float* __restrict__ wq,
    const float* __restrict__ wk, const float* __restrict__ wv,
    const float* __restrict__ wo, const float* __restrict__ bq,
    const float* __restrict__ bk, const float* __restrict__ bv,
    bf16* __restrict__ xb, bf16* __restrict__ wqkvt, bf16* __restrict__ wot,
    float* __restrict__ bqkv) {
  int blk = blockIdx.x;
  int tid = threadIdx.x;
  if (blk < 2048) {
    int i = blk * 256 + tid;
    const float4* p = (const float4*)x + (size_t)i * 2;
    float4 f0 = p[0], f1 = p[1];
    bf16x8 o;
    o[0] = (bf16)f0.x; o[1] = (bf16)f0.y; o[2] = (bf16)f0.z; o[3] = (bf16)f0.w;
    o[4] = (bf16)f1.x; o[5] = (bf16)f1.y; o[6] = (bf16)f1.z; o[7] = (bf16)f1.w;
    *((bf16x8*)xb + i) = o;
    return;
  }
  if (blk >= 3072) {
    int i = (blk - 3072) * 256 + tid;
    if (i < 1024) bqkv[i] = bq[i];
    else if (i < 2048) bqkv[i] = bk[i - 1024];
    else if (i < 3072) bqkv[i] = bv[i - 2048];
    return;
  }
  __shared__ float t[64][68];
  int sub = blk - 2048;
  int wsel = sub >> 8;
  sub &= 255;
  const float* in = wsel == 0 ? wq : wsel == 1 ? wk : wsel == 2 ? wv : wo;
  bf16* out = (wsel == 3) ? wot : (wqkvt + (size_t)wsel * (1u << 20));
  int bx = sub & 15;
  int by = sub >> 4;
  int r = tid >> 2, p = tid & 3;
  const float* src = in + (size_t)(by * 64 + r) * 1024 + bx * 64 + p * 16;
#pragma unroll
  for (int j = 0; j < 16; j += 4)
    *(float4*)&t[r][p * 16 + j] = *(const float4*)(src + j);
  __syncthreads();
  int n = tid >> 2, sp = tid & 3;
  bf16 tmp[16];
#pragma unroll
  for (int j = 0; j < 16; ++j) tmp[j] = (bf16)t[sp * 16 + j][n];
  bf16* dst = out + (size_t)(bx * 64 + n) * 1024 + by * 64 + sp * 16;
  *(bf16x8*)dst = *(bf16x8*)&tmp[0];
  *(bf16x8*)(dst + 8) = *(bf16x8*)&tmp[8];
}

// ---------------- parallel deterministic stable sort of lag by rank ----------------
__global__ __launch_bounds__(256) void sort_lag_kernel(const int* __restrict__ lag,
                                                       int* __restrict__ perm,
                                                       int* __restrict__ slag) {
  __shared__ int l[2048];
  int tid = threadIdx.x;
  for (int i = tid; i < 2048; i += 256) l[i] = lag[i];
  __syncthreads();
  int i = blockIdx.x * 32 + (tid >> 3);
  int s = tid & 7;
  int vi = l[i];
  int cnt = 0;
  for (int j = s * 256; j < s * 256 + 256; j += 4) {
    int4 vj = *(const int4*)&l[j];
    cnt += (vj.x < vi || (vj.x == vi && (j + 0) < i));
    cnt += (vj.y < vi || (vj.y == vi && (j + 1) < i));
    cnt += (vj.z < vi || (vj.z == vi && (j + 2) < i));
    cnt += (vj.w < vi || (vj.w == vi && (j + 3) < i));
  }
  cnt += __shfl_xor(cnt, 1);
  cnt += __shfl_xor(cnt, 2);
  cnt += __shfl_xor(cnt, 4);
  if (s == 0) { perm[cnt] = i; slag[cnt] = vi; }
}

// ---- pack K rows sorted (kp[(b*16+h)*2048+ss][64]) + V transpose sorted (vt[bh][d][ss]) ----
__global__ __launch_bounds__(256) void pack_kv_kernel(const bf16* __restrict__ qkv,
                                                      const int* __restrict__ perm,
                                                      bf16* __restrict__ kp,
                                                      bf16* __restrict__ vt) {
  __shared__ bf16 t[64][72];
  int blk = blockIdx.x;
  int st = blk & 31, h = (blk >> 5) & 15, b = blk >> 9;
  int tid = threadIdx.x;
  int r = tid >> 2, p = tid & 3;
  int src_s = perm[st * 64 + r];
  {
    const bf16* src = qkv + (size_t)(b * 2048 + src_s) * 3072 + 1024 + h * 64 + p * 16;
    bf16* dst = kp + (size_t)((b * 16 + h) * 2048 + st * 64 + r) * 64 + p * 16;
    *(bf16x8*)dst = *(const bf16x8*)src;
    *(bf16x8*)(dst + 8) = *(const bf16x8*)(src + 8);
  }
  {
    const bf16* src = qkv + (size_t)(b * 2048 + src_s) * 3072 + 2048 + h * 64 + p * 16;
    *(bf16x8*)&t[r][p * 16] = *(const bf16x8*)src;
    *(bf16x8*)&t[r][p * 16 + 8] = *(const bf16x8*)(src + 8);
    __syncthreads();
    int d = tid >> 2, sp = tid & 3;
    bf16 tmp[16];
#pragma unroll
    for (int j = 0; j < 16; ++j) tmp[j] = t[sp * 16 + j][d];
    bf16* dst = vt + (size_t)((b * 16 + h) * 64 + d) * 2048 + st * 64 + sp * 16;
    *(bf16x8*)dst = *(bf16x8*)&tmp[0];
    *(bf16x8*)(dst + 8) = *(bf16x8*)&tmp[8];
  }
}

// ---------------- bf16 GEMM: C[M][N] = A[M][K] * Bt[N][K]^T + bias, optional col-scale ----------------
template <int OUT_BF16>
__global__ __launch_bounds__(256) void gemm_bt_kernel(
    const bf16* __restrict__ A, const bf16* __restrict__ Bt,
    const float* __restrict__ bias, void* __restrict__ C,
    int M, int N, int K, int scale_cols, float scale_val) {
  __shared__ __align__(16) bf16 As[128 * 64];
  __shared__ __align__(16) bf16 Bs[128 * 64];
  int bn = blockIdx.x * 128, bm = blockIdx.y * 128;
  int tid = threadIdx.x;
  int l = tid & 63;
  int w = tid >> 6;
  int wr = w >> 1, wc = w & 1;
  int g = l >> 4, c = l & 15;
  int swz = (c & 7) << 3;
  int srow = l >> 3;
  int scol = ((l & 7) ^ srow) << 3;
  const bf16* Ap = A + (size_t)(bm + w * 32 + srow) * K + scol;
  const bf16* Bp = Bt + (size_t)(bn + w * 32 + srow) * K + scol;
  bf16* AsW = As + w * 32 * 64;
  bf16* BsW = Bs + w * 32 * 64;

  f32x4 acc[4][4] = {};
  for (int k0 = 0; k0 < K; k0 += 64) {
    __syncthreads();
#pragma unroll
    for (int i = 0; i < 4; ++i) {
      gload16(Ap + (size_t)(8 * i) * K + k0, AsW + i * 512);
      gload16(Bp + (size_t)(8 * i) * K + k0, BsW + i * 512);
    }
    __syncthreads();
#pragma unroll
    for (int kh = 0; kh < 2; ++kh) {
      bf16x8 af[4], bfr[4];
#pragma unroll
      for (int m = 0; m < 4; ++m)
        af[m] = *(const bf16x8*)&As[(wr * 64 + m * 16 + c) * 64 + ((kh * 32 + g * 8) ^ swz)];
#pragma unroll
      for (int n = 0; n < 4; ++n)
        bfr[n] = *(const bf16x8*)&Bs[(wc * 64 + n * 16 + c) * 64 + ((kh * 32 + g * 8) ^ swz)];
#pragma unroll
      for (int m = 0; m < 4; ++m)
#pragma unroll
        for (int n = 0; n < 4; ++n)
          acc[m][n] = mfma16(af[m], bfr[n], acc[m][n]);
    }
  }
  int rowb = bm + wr * 64;
  int colb = bn + wc * 64;
#pragma unroll
  for (int n = 0; n < 4; ++n) {
    int col = colb + n * 16 + c;
    float bv = bias[col];
    float s = (col < scale_cols) ? scale_val : 1.0f;
#pragma unroll
    for (int m = 0; m < 4; ++m) {
      int row = rowb + m * 16 + g * 4;
#pragma unroll
      for (int j = 0; j < 4; ++j) {
        float v = (acc[m][n][j] + bv) * s;
        if (OUT_BF16)
          ((bf16*)C)[(size_t)(row + j) * N + col] = (bf16)v;
        else
          ((float*)C)[(size_t)(row + j) * N + col] = v;
      }
    }
  }
}

// ---------------- flash attention (sorted keys, 8 waves x 32q = 256q/block) ----------------
// grid 256 = qt8 x h16 x b2 (XCD-swizzled); 512 threads; 2 blocks/CU => 16 waves/CU.
// Per-wave compute byte-identical to R10's validated 32q TILE. Single-buffered K/V
// (R2/R5 showed dbuf is time-neutral; LDS spent on waves instead). Staging: 512 thr
// cover the 8KB tile with 1 gload16 each, same XOR swizzle formula.
__global__ __launch_bounds__(512, 4) void attn_kernel(
    const bf16* __restrict__ qkv, const bf16* __restrict__ kp,
    const bf16* __restrict__ vt, const int* __restrict__ lag,
    const int* __restrict__ slag, const float* __restrict__ lag_bias,
    bf16* __restrict__ out) {
  __shared__ __align__(16) bf16 Ks[64 * 64];
  __shared__ __align__(16) bf16 Vs[64 * 64];
  __shared__ __align__(16) bf16 Ps[8][32][72];
  __shared__ float bias_s[516];
  __shared__ int lag_s[2048];   // sorted lag (keys)

  int blk = blockIdx.x;
  blk = (blk & 7) * 32 + (blk >> 3);  // bijective XCD swizzle (256 % 8 == 0)
  int qt = blk & 7;
  int h = (blk >> 3) & 15;
  int b = blk >> 7;
  int tid = threadIdx.x;
  int w = tid >> 6, l = tid & 63, g = l >> 4, c = l & 15;

  for (int i = tid; i < 513; i += 512) bias_s[i] = lag_bias[h * 513 + i] * 1.44269504f;
  for (int i = tid; i < 2048; i += 512) lag_s[i] = slag[i];

  int q0 = qt * 256 + w * 32;
  const bf16* qbase = qkv + (size_t)(b * 2048 + q0) * 3072 + h * 64;
  bf16x8 qf[2][2];
#pragma unroll
  for (int m = 0; m < 2; ++m)
#pragma unroll
    for (int kh = 0; kh < 2; ++kh)
      qf[m][kh] = *(const bf16x8*)(qbase + (size_t)(m * 16 + c) * 3072 + kh * 32 + g * 8);

  int lagq[2][4];
#pragma unroll
  for (int m = 0; m < 2; ++m)
#pragma unroll
    for (int j = 0; j < 4; ++j) lagq[m][j] = lag[q0 + m * 16 + g * 4 + j];

  // fragment-read column offsets (XOR-swizzled LDS layout)
  int swz = (c & 7) << 3;
  int off0 = (g * 8) ^ swz;
  int off1 = off0 ^ 32;

  // staging: 512 threads x 16B = one 64x64 tile; thread covers row tid>>3, chunk tid&7
  int r0 = tid >> 3;                         // 0..63
  int colE = ((tid & 7) ^ (r0 & 7)) << 3;    // inverse-swizzled global column (elems)
  const bf16* kg = kp + (size_t)(b * 16 + h) * 2048 * 64 + (size_t)r0 * 64 + colE;
  const bf16* vg = vt + (size_t)(b * 16 + h) * 64 * 2048 + (size_t)r0 * 2048 + colE;
  bf16* kl = Ks + w * 512;   // wave-uniform LDS dest (lane x 16B appended by HW)
  bf16* vl = Vs + w * 512;

  __syncthreads();  // bias_s / lag_s ready

  f32x4 oacc[2][4] = {};
  float psum[2][4] = {};

  for (int kt = 0; kt < 2048; kt += 64) {
    gload16(kg, kl);
    gload16(vg, vl);
    kg += 64 * 64;
    vg += 64;
    __syncthreads();  // vmcnt drained => tile ready

    // QK^T: S[q = m*16 + g*4+j][key = kb*16+c]
    f32x4 sf[2][4] = {};
    int lagk[4];
#pragma unroll
    for (int kb = 0; kb < 4; ++kb) {
      int row = kb * 16 + c;
      bf16x8 k0 = *(const bf16x8*)&Ks[row * 64 + off0];
      bf16x8 k1 = *(const bf16x8*)&Ks[row * 64 + off1];
      sf[0][kb] = mfma16(qf[0][0], k0, sf[0][kb]);
      sf[0][kb] = mfma16(qf[0][1], k1, sf[0][kb]);
      sf[1][kb] = mfma16(qf[1][0], k0, sf[1][kb]);
      sf[1][kb] = mfma16(qf[1][1], k1, sf[1][kb]);
      lagk[kb] = lag_s[kt + kb * 16 + c];
    }
    // no-max softmax (sorted keys => bias gathers near-broadcast)
#pragma unroll
    for (int m = 0; m < 2; ++m)
#pragma unroll
      for (int kb = 0; kb < 4; ++kb)
#pragma unroll
        for (int j = 0; j < 4; ++j) {
          int ld = lagq[m][j] - lagk[kb];
          ld = ld < 0 ? -ld : ld;
          float p = __builtin_amdgcn_exp2f(sf[m][kb][j] + bias_s[ld]);
          psum[m][j] += p;
          Ps[w][m * 16 + g * 4 + j][kb * 16 + c] = (bf16)p;
        }
    asm volatile("s_waitcnt lgkmcnt(0)" ::: "memory");
#pragma unroll
    for (int ph = 0; ph < 2; ++ph) {
      bf16x8 pa0 = *(const bf16x8*)&Ps[w][c][ph * 32 + g * 8];
      bf16x8 pa1 = *(const bf16x8*)&Ps[w][16 + c][ph * 32 + g * 8];
      int voff = ph ? off1 : off0;
#pragma unroll
      for (int n = 0; n < 4; ++n) {
        bf16x8 vf = *(const bf16x8*)&Vs[(n * 16 + c) * 64 + voff];
        oacc[0][n] = mfma16(pa0, vf, oacc[0][n]);
        oacc[1][n] = mfma16(pa1, vf, oacc[1][n]);
      }
    }
    __syncthreads();  // close tile reads before next staging overwrites
  }

  // one-time row-sum reduction across the 16 c-lanes, then normalize+store
#pragma unroll
  for (int m = 0; m < 2; ++m) {
#pragma unroll
    for (int j = 0; j < 4; ++j) {
      float s = psum[m][j];
      s += __shfl_xor(s, 1);
      s += __shfl_xor(s, 2);
      s += __shfl_xor(s, 4);
      s += __shfl_xor(s, 8);
      float inv = 1.f / s;
      bf16* ob = out + (size_t)(b * 2048 + q0 + m * 16 + g * 4 + j) * 1024 + h * 64;
#pragma unroll
      for (int n = 0; n < 4; ++n)
        ob[n * 16 + c] = (bf16)(oacc[m][n][j] * inv);
    }
  }
}

extern "C" void kernel_launch(void* const* d_in, const int* in_sizes, int n_in,
                              void* d_out, int out_size, void* d_ws, size_t ws_size,
                              hipStream_t stream) {
  const float* x        = (const float*)d_in[0];
  const int*   lag      = (const int*)d_in[1];
  const float* wq       = (const float*)d_in[2];
  const float* bq       = (const float*)d_in[3];
  const float* wk       = (const float*)d_in[4];
  const float* bk       = (const float*)d_in[5];
  const float* wv       = (const float*)d_in[6];
  const float* bv       = (const float*)d_in[7];
  const float* wo       = (const float*)d_in[8];
  const float* bo       = (const float*)d_in[9];
  const float* lag_bias = (const float*)d_in[10];

  char* ws = (char*)d_ws;
  bf16*  xb    = (bf16*)ws;                        // 8 MB (x bf16; reused as kp after QKV GEMM)
  bf16*  wqkvt = (bf16*)(ws + (8u  << 20));        // 6 MB
  bf16*  wot   = (bf16*)(ws + (14u << 20));        // 2 MB
  float* bqkv  = (float*)(ws + (16u << 20));       // 12 KB
  int*   perm  = (int*)(ws + (16u << 20) + 32768); // 8 KB
  int*   slag  = (int*)(ws + (16u << 20) + 65536); // 8 KB
  bf16*  qkv   = (bf16*)(ws + (17u << 20));        // 24 MB
  bf16*  vtb   = (bf16*)(ws + (41u << 20));        // 8 MB
  bf16*  aout  = (bf16*)(ws + (49u << 20));        // 8 MB
  bf16*  kpk   = xb;                               // packed sorted K (xb dead after GEMM)

  sort_lag_kernel<<<64, 256, 0, stream>>>(lag, perm, slag);
  prep_kernel<<<3084, 256, 0, stream>>>(x, wq, wk, wv, wo, bq, bk, bv,
                                        xb, wqkvt, wot, bqkv);
  gemm_bt_kernel<1><<<dim3(24, 32), 256, 0, stream>>>(
      xb, wqkvt, bqkv, qkv, 4096, 3072, 1024, 1024, 0.125f * 1.44269504f);
  pack_kv_kernel<<<1024, 256, 0, stream>>>(qkv, perm, kpk, vtb);
  attn_kernel<<<256, 512, 0, stream>>>(qkv, kpk, vtb, lag, slag, lag_bias, aout);
  gemm_bt_kernel<0><<<dim3(8, 32), 256, 0, stream>>>(
      aout, wot, bo, (float*)d_out, 4096, 1024, 1024, 0, 1.0f);
}

// Round 14
// 161.702 us; speedup vs baseline: 2.0278x; 1.1071x over previous
//
#include <hip/hip_runtime.h>

typedef __bf16 bf16;
typedef __bf16 bf16x8 __attribute__((ext_vector_type(8)));
typedef float f32x4 __attribute__((ext_vector_type(4)));

__device__ __forceinline__ f32x4 mfma16(bf16x8 a, bf16x8 b, f32x4 c) {
  return __builtin_amdgcn_mfma_f32_16x16x32_bf16(a, b, c, 0, 0, 0);
}
__device__ __forceinline__ void gload16(const bf16* g, bf16* l) {
  __builtin_amdgcn_global_load_lds((const __attribute__((address_space(1))) unsigned int*)g,
                                   (__attribute__((address_space(3))) unsigned int*)l, 16, 0, 0);
}

// ------- fused prep: x f32->bf16 (blocks 0..2047), 4x weight transpose (2048..3071),
//         bias concat (3072..3083). grid 3084 -------
__global__ __launch_bounds__(256) void prep_kernel(
    const float* __restrict__ x, const float* __restrict__ wq,
    const float* __restrict__ wk, const float* __restrict__ wv,
    const float* __restrict__ wo, const float* __restrict__ bq,
    const float* __restrict__ bk, const float* __restrict__ bv,
    bf16* __restrict__ xb, bf16* __restrict__ wqkvt, bf16* __restrict__ wot,
    float* __restrict__ bqkv) {
  int blk = blockIdx.x;
  int tid = threadIdx.x;
  if (blk < 2048) {
    int i = blk * 256 + tid;
    const float4* p = (const float4*)x + (size_t)i * 2;
    float4 f0 = p[0], f1 = p[1];
    bf16x8 o;
    o[0] = (bf16)f0.x; o[1] = (bf16)f0.y; o[2] = (bf16)f0.z; o[3] = (bf16)f0.w;
    o[4] = (bf16)f1.x; o[5] = (bf16)f1.y; o[6] = (bf16)f1.z; o[7] = (bf16)f1.w;
    *((bf16x8*)xb + i) = o;
    return;
  }
  if (blk >= 3072) {
    int i = (blk - 3072) * 256 + tid;
    if (i < 1024) bqkv[i] = bq[i];
    else if (i < 2048) bqkv[i] = bk[i - 1024];
    else if (i < 3072) bqkv[i] = bv[i - 2048];
    return;
  }
  __shared__ float t[64][68];
  int sub = blk - 2048;
  int wsel = sub >> 8;
  sub &= 255;
  const float* in = wsel == 0 ? wq : wsel == 1 ? wk : wsel == 2 ? wv : wo;
  bf16* out = (wsel == 3) ? wot : (wqkvt + (size_t)wsel * (1u << 20));
  int bx = sub & 15;
  int by = sub >> 4;
  int r = tid >> 2, p = tid & 3;
  const float* src = in + (size_t)(by * 64 + r) * 1024 + bx * 64 + p * 16;
#pragma unroll
  for (int j = 0; j < 16; j += 4)
    *(float4*)&t[r][p * 16 + j] = *(const float4*)(src + j);
  __syncthreads();
  int n = tid >> 2, sp = tid & 3;
  bf16 tmp[16];
#pragma unroll
  for (int j = 0; j < 16; ++j) tmp[j] = (bf16)t[sp * 16 + j][n];
  bf16* dst = out + (size_t)(bx * 64 + n) * 1024 + by * 64 + sp * 16;
  *(bf16x8*)dst = *(bf16x8*)&tmp[0];
  *(bf16x8*)(dst + 8) = *(bf16x8*)&tmp[8];
}

// ---------------- parallel deterministic stable sort of lag by rank ----------------
__global__ __launch_bounds__(256) void sort_lag_kernel(const int* __restrict__ lag,
                                                       int* __restrict__ perm,
                                                       int* __restrict__ slag) {
  __shared__ int l[2048];
  int tid = threadIdx.x;
  for (int i = tid; i < 2048; i += 256) l[i] = lag[i];
  __syncthreads();
  int i = blockIdx.x * 32 + (tid >> 3);
  int s = tid & 7;
  int vi = l[i];
  int cnt = 0;
  for (int j = s * 256; j < s * 256 + 256; j += 4) {
    int4 vj = *(const int4*)&l[j];
    cnt += (vj.x < vi || (vj.x == vi && (j + 0) < i));
    cnt += (vj.y < vi || (vj.y == vi && (j + 1) < i));
    cnt += (vj.z < vi || (vj.z == vi && (j + 2) < i));
    cnt += (vj.w < vi || (vj.w == vi && (j + 3) < i));
  }
  cnt += __shfl_xor(cnt, 1);
  cnt += __shfl_xor(cnt, 2);
  cnt += __shfl_xor(cnt, 4);
  if (s == 0) { perm[cnt] = i; slag[cnt] = vi; }
}

// ---- pack K rows sorted (kp[(b*16+h)*2048+ss][64]) + V transpose sorted (vt[bh][d][ss]) ----
__global__ __launch_bounds__(256) void pack_kv_kernel(const bf16* __restrict__ qkv,
                                                      const int* __restrict__ perm,
                                                      bf16* __restrict__ kp,
                                                      bf16* __restrict__ vt) {
  __shared__ bf16 t[64][72];
  int blk = blockIdx.x;
  int st = blk & 31, h = (blk >> 5) & 15, b = blk >> 9;
  int tid = threadIdx.x;
  int r = tid >> 2, p = tid & 3;
  int src_s = perm[st * 64 + r];
  {
    const bf16* src = qkv + (size_t)(b * 2048 + src_s) * 3072 + 1024 + h * 64 + p * 16;
    bf16* dst = kp + (size_t)((b * 16 + h) * 2048 + st * 64 + r) * 64 + p * 16;
    *(bf16x8*)dst = *(const bf16x8*)src;
    *(bf16x8*)(dst + 8) = *(const bf16x8*)(src + 8);
  }
  {
    const bf16* src = qkv + (size_t)(b * 2048 + src_s) * 3072 + 2048 + h * 64 + p * 16;
    *(bf16x8*)&t[r][p * 16] = *(const bf16x8*)src;
    *(bf16x8*)&t[r][p * 16 + 8] = *(const bf16x8*)(src + 8);
    __syncthreads();
    int d = tid >> 2, sp = tid & 3;
    bf16 tmp[16];
#pragma unroll
    for (int j = 0; j < 16; ++j) tmp[j] = t[sp * 16 + j][d];
    bf16* dst = vt + (size_t)((b * 16 + h) * 64 + d) * 2048 + st * 64 + sp * 16;
    *(bf16x8*)dst = *(bf16x8*)&tmp[0];
    *(bf16x8*)(dst + 8) = *(bf16x8*)&tmp[8];
  }
}

// ---------------- bf16 GEMM 128x128 (QKV projection): C = A * Bt^T + bias, col-scale ----------------
template <int OUT_BF16>
__global__ __launch_bounds__(256) void gemm_bt_kernel(
    const bf16* __restrict__ A, const bf16* __restrict__ Bt,
    const float* __restrict__ bias, void* __restrict__ C,
    int M, int N, int K, int scale_cols, float scale_val) {
  __shared__ __align__(16) bf16 As[128 * 64];
  __shared__ __align__(16) bf16 Bs[128 * 64];
  int bn = blockIdx.x * 128, bm = blockIdx.y * 128;
  int tid = threadIdx.x;
  int l = tid & 63;
  int w = tid >> 6;
  int wr = w >> 1, wc = w & 1;
  int g = l >> 4, c = l & 15;
  int swz = (c & 7) << 3;
  int srow = l >> 3;
  int scol = ((l & 7) ^ srow) << 3;
  const bf16* Ap = A + (size_t)(bm + w * 32 + srow) * K + scol;
  const bf16* Bp = Bt + (size_t)(bn + w * 32 + srow) * K + scol;
  bf16* AsW = As + w * 32 * 64;
  bf16* BsW = Bs + w * 32 * 64;

  f32x4 acc[4][4] = {};
  for (int k0 = 0; k0 < K; k0 += 64) {
    __syncthreads();
#pragma unroll
    for (int i = 0; i < 4; ++i) {
      gload16(Ap + (size_t)(8 * i) * K + k0, AsW + i * 512);
      gload16(Bp + (size_t)(8 * i) * K + k0, BsW + i * 512);
    }
    __syncthreads();
#pragma unroll
    for (int kh = 0; kh < 2; ++kh) {
      bf16x8 af[4], bfr[4];
#pragma unroll
      for (int m = 0; m < 4; ++m)
        af[m] = *(const bf16x8*)&As[(wr * 64 + m * 16 + c) * 64 + ((kh * 32 + g * 8) ^ swz)];
#pragma unroll
      for (int n = 0; n < 4; ++n)
        bfr[n] = *(const bf16x8*)&Bs[(wc * 64 + n * 16 + c) * 64 + ((kh * 32 + g * 8) ^ swz)];
#pragma unroll
      for (int m = 0; m < 4; ++m)
#pragma unroll
        for (int n = 0; n < 4; ++n)
          acc[m][n] = mfma16(af[m], bfr[n], acc[m][n]);
    }
  }
  int rowb = bm + wr * 64;
  int colb = bn + wc * 64;
#pragma unroll
  for (int n = 0; n < 4; ++n) {
    int col = colb + n * 16 + c;
    float bv = bias[col];
    float s = (col < scale_cols) ? scale_val : 1.0f;
#pragma unroll
    for (int m = 0; m < 4; ++m) {
      int row = rowb + m * 16 + g * 4;
#pragma unroll
      for (int j = 0; j < 4; ++j) {
        float v = (acc[m][n][j] + bv) * s;
        if (OUT_BF16)
          ((bf16*)C)[(size_t)(row + j) * N + col] = (bf16)v;
        else
          ((float*)C)[(size_t)(row + j) * N + col] = v;
      }
    }
  }
}

// ---------------- bf16 GEMM 64x128 tile (out-projection): grid (N/128, M/64) ----------------
// 4 waves split by COLUMN: wave w covers cols w*32..w*32+31, all 64 rows. acc[4][2].
// Same fragment math / staging pattern / XOR swizzle as gemm_bt_kernel.
__global__ __launch_bounds__(256) void gemm64_kernel(
    const bf16* __restrict__ A, const bf16* __restrict__ Bt,
    const float* __restrict__ bias, float* __restrict__ C,
    int M, int N, int K) {
  __shared__ __align__(16) bf16 As[64 * 64];
  __shared__ __align__(16) bf16 Bs[128 * 64];
  int bn = blockIdx.x * 128, bm = blockIdx.y * 64;
  int tid = threadIdx.x;
  int l = tid & 63;
  int w = tid >> 6;
  int g = l >> 4, c = l & 15;
  int swz = (c & 7) << 3;
  int srow = l >> 3;
  int scol = ((l & 7) ^ srow) << 3;
  const bf16* Ap = A + (size_t)(bm + w * 16 + srow) * K + scol;   // 2 chunks of 8 rows
  const bf16* Bp = Bt + (size_t)(bn + w * 32 + srow) * K + scol;  // 4 chunks of 8 rows
  bf16* AsW = As + w * 16 * 64;
  bf16* BsW = Bs + w * 32 * 64;

  f32x4 acc[4][2] = {};
  for (int k0 = 0; k0 < K; k0 += 64) {
    __syncthreads();
#pragma unroll
    for (int i = 0; i < 2; ++i)
      gload16(Ap + (size_t)(8 * i) * K + k0, AsW + i * 512);
#pragma unroll
    for (int i = 0; i < 4; ++i)
      gload16(Bp + (size_t)(8 * i) * K + k0, BsW + i * 512);
    __syncthreads();
#pragma unroll
    for (int kh = 0; kh < 2; ++kh) {
      int koff = (kh * 32 + g * 8) ^ swz;
      bf16x8 af[4], bfr[2];
#pragma unroll
      for (int m = 0; m < 4; ++m)
        af[m] = *(const bf16x8*)&As[(m * 16 + c) * 64 + koff];
#pragma unroll
      for (int n = 0; n < 2; ++n)
        bfr[n] = *(const bf16x8*)&Bs[(w * 32 + n * 16 + c) * 64 + koff];
#pragma unroll
      for (int m = 0; m < 4; ++m)
#pragma unroll
        for (int n = 0; n < 2; ++n)
          acc[m][n] = mfma16(af[m], bfr[n], acc[m][n]);
    }
  }
#pragma unroll
  for (int n = 0; n < 2; ++n) {
    int col = bn + w * 32 + n * 16 + c;
    float bv = bias[col];
#pragma unroll
    for (int m = 0; m < 4; ++m) {
      int row = bm + m * 16 + g * 4;
#pragma unroll
      for (int j = 0; j < 4; ++j)
        C[(size_t)(row + j) * N + col] = acc[m][n][j] + bv;
    }
  }
}

// ---------------- flash attention (sorted keys, 32 q/wave, mirrored bias table) ----------------
// R10-validated config: grid 512 = qt16 x h16 x b2 (XCD-swizzled), 4 waves x 32 q,
// distinct-LDS double-buffer, packed sorted K + sorted V^T. New: bias2[i]=bias[|i-512|]
// mirrored table removes the per-score abs (lagq preloaded +512).
__global__ __launch_bounds__(256) void attn_kernel(
    const bf16* __restrict__ qkv, const bf16* __restrict__ kp,
    const bf16* __restrict__ vt, const int* __restrict__ lag,
    const int* __restrict__ slag, const float* __restrict__ lag_bias,
    bf16* __restrict__ out) {
  __shared__ __align__(16) bf16 Ks0[64 * 64];
  __shared__ __align__(16) bf16 Vs0[64 * 64];
  __shared__ __align__(16) bf16 Ks1[64 * 64];
  __shared__ __align__(16) bf16 Vs1[64 * 64];
  __shared__ __align__(16) bf16 Ps[4][32][72];
  __shared__ float bias2_s[1028];
  __shared__ int lag_s[2048];   // sorted lag (keys)

  int blk = blockIdx.x;
  blk = (blk & 7) * 64 + (blk >> 3);  // bijective XCD swizzle (512 % 8 == 0)
  int qt = blk & 15;
  int h = (blk >> 4) & 15;
  int b = blk >> 8;
  int tid = threadIdx.x;
  int w = tid >> 6, l = tid & 63, g = l >> 4, c = l & 15;

  for (int i = tid; i < 1025; i += 256) {
    int d = i - 512;
    d = d < 0 ? -d : d;
    bias2_s[i] = lag_bias[h * 513 + d] * 1.44269504f;
  }
  for (int i = tid; i < 2048; i += 256) lag_s[i] = slag[i];

  int q0 = qt * 128 + w * 32;
  const bf16* qbase = qkv + (size_t)(b * 2048 + q0) * 3072 + h * 64;
  bf16x8 qf[2][2];
#pragma unroll
  for (int m = 0; m < 2; ++m)
#pragma unroll
    for (int kh = 0; kh < 2; ++kh)
      qf[m][kh] = *(const bf16x8*)(qbase + (size_t)(m * 16 + c) * 3072 + kh * 32 + g * 8);

  int lagq[2][4];
#pragma unroll
  for (int m = 0; m < 2; ++m)
#pragma unroll
    for (int j = 0; j < 4; ++j) lagq[m][j] = lag[q0 + m * 16 + g * 4 + j] + 512;

  // fragment-read column offsets (XOR-swizzled LDS layout)
  int swz = (c & 7) << 3;
  int off0 = (g * 8) ^ swz;
  int off1 = off0 ^ 32;

  // staging: thread covers 16B; wave w owns rows w*16..w*16+15 (two 8-row chunks)
  int r0 = w * 16 + (l >> 3);
  int colE = ((l & 7) ^ (l >> 3)) << 3;  // inverse-swizzled global column
  const bf16* kbase = kp + (size_t)(b * 16 + h) * 2048 * 64;
  const bf16* vbase = vt + (size_t)(b * 16 + h) * 64 * 2048;
  const bf16* kg0 = kbase + (size_t)r0 * 64 + colE;
  const bf16* kg1 = kbase + (size_t)(r0 + 8) * 64 + colE;
  const bf16* vg0 = vbase + (size_t)r0 * 2048 + colE;
  const bf16* vg1 = vbase + (size_t)(r0 + 8) * 2048 + colE;

#define STAGE(KD, VD)                    \
  do {                                   \
    gload16(kg0, KD + w * 1024);         \
    gload16(kg1, KD + w * 1024 + 512);   \
    gload16(vg0, VD + w * 1024);         \
    gload16(vg1, VD + w * 1024 + 512);   \
    kg0 += 64 * 64; kg1 += 64 * 64;      \
    vg0 += 64; vg1 += 64;                \
  } while (0)

  STAGE(Ks0, Vs0);
  __syncthreads();

  f32x4 oacc[2][4] = {};
  float psum[2][4] = {};

#define TILE(KB, VB, KT)                                                          \
  do {                                                                            \
    f32x4 sf[2][4] = {};                                                          \
    int lagk[4];                                                                  \
    _Pragma("unroll") for (int kb = 0; kb < 4; ++kb) {                            \
      int row = kb * 16 + c;                                                      \
      bf16x8 k0 = *(const bf16x8*)&KB[row * 64 + off0];                           \
      bf16x8 k1 = *(const bf16x8*)&KB[row * 64 + off1];                           \
      sf[0][kb] = mfma16(qf[0][0], k0, sf[0][kb]);                                \
      sf[0][kb] = mfma16(qf[0][1], k1, sf[0][kb]);                                \
      sf[1][kb] = mfma16(qf[1][0], k0, sf[1][kb]);                                \
      sf[1][kb] = mfma16(qf[1][1], k1, sf[1][kb]);                                \
      lagk[kb] = lag_s[(KT) + kb * 16 + c];                                       \
    }                                                                             \
    _Pragma("unroll") for (int m = 0; m < 2; ++m)                                 \
    _Pragma("unroll") for (int kb = 0; kb < 4; ++kb)                              \
    _Pragma("unroll") for (int j = 0; j < 4; ++j) {                               \
      int ld = lagq[m][j] - lagk[kb];                                             \
      float p = __builtin_amdgcn_exp2f(sf[m][kb][j] + bias2_s[ld]);               \
      psum[m][j] += p;                                                            \
      Ps[w][m * 16 + g * 4 + j][kb * 16 + c] = (bf16)p;                           \
    }                                                                             \
    asm volatile("s_waitcnt lgkmcnt(0)" ::: "memory");                            \
    _Pragma("unroll") for (int ph = 0; ph < 2; ++ph) {                            \
      bf16x8 pa0 = *(const bf16x8*)&Ps[w][c][ph * 32 + g * 8];                    \
      bf16x8 pa1 = *(const bf16x8*)&Ps[w][16 + c][ph * 32 + g * 8];               \
      int voff = ph ? off1 : off0;                                                \
      _Pragma("unroll") for (int n = 0; n < 4; ++n) {                             \
        bf16x8 vf = *(const bf16x8*)&VB[(n * 16 + c) * 64 + voff];                \
        oacc[0][n] = mfma16(pa0, vf, oacc[0][n]);                                 \
        oacc[1][n] = mfma16(pa1, vf, oacc[1][n]);                                 \
      }                                                                           \
    }                                                                             \
  } while (0)

  for (int kt = 0; kt < 2048; kt += 128) {
    if (kt + 64 < 2048) STAGE(Ks1, Vs1);
    TILE(Ks0, Vs0, kt);
    __syncthreads();  // drains vmcnt: Ks1/Vs1 ready; closes Ks0/Vs0 reads
    if (kt + 128 < 2048) STAGE(Ks0, Vs0);
    TILE(Ks1, Vs1, kt + 64);
    __syncthreads();
  }

  // one-time row-sum reduction across the 16 c-lanes, then normalize+store
#pragma unroll
  for (int m = 0; m < 2; ++m) {
#pragma unroll
    for (int j = 0; j < 4; ++j) {
      float s = psum[m][j];
      s += __shfl_xor(s, 1);
      s += __shfl_xor(s, 2);
      s += __shfl_xor(s, 4);
      s += __shfl_xor(s, 8);
      float inv = 1.f / s;
      bf16* ob = out + (size_t)(b * 2048 + q0 + m * 16 + g * 4 + j) * 1024 + h * 64;
#pragma unroll
      for (int n = 0; n < 4; ++n)
        ob[n * 16 + c] = (bf16)(oacc[m][n][j] * inv);
    }
  }
#undef STAGE
#undef TILE
}

extern "C" void kernel_launch(void* const* d_in, const int* in_sizes, int n_in,
                              void* d_out, int out_size, void* d_ws, size_t ws_size,
                              hipStream_t stream) {
  const float* x        = (const float*)d_in[0];
  const int*   lag      = (const int*)d_in[1];
  const float* wq       = (const float*)d_in[2];
  const float* bq       = (const float*)d_in[3];
  const float* wk       = (const float*)d_in[4];
  const float* bk       = (const float*)d_in[5];
  const float* wv       = (const float*)d_in[6];
  const float* bv       = (const float*)d_in[7];
  const float* wo       = (const float*)d_in[8];
  const float* bo       = (const float*)d_in[9];
  const float* lag_bias = (const float*)d_in[10];

  char* ws = (char*)d_ws;
  bf16*  xb    = (bf16*)ws;                        // 8 MB (x bf16; reused as kp after QKV GEMM)
  bf16*  wqkvt = (bf16*)(ws + (8u  << 20));        // 6 MB
  bf16*  wot   = (bf16*)(ws + (14u << 20));        // 2 MB
  float* bqkv  = (float*)(ws + (16u << 20));       // 12 KB
  int*   perm  = (int*)(ws + (16u << 20) + 32768); // 8 KB
  int*   slag  = (int*)(ws + (16u << 20) + 65536); // 8 KB
  bf16*  qkv   = (bf16*)(ws + (17u << 20));        // 24 MB
  bf16*  vtb   = (bf16*)(ws + (41u << 20));        // 8 MB
  bf16*  aout  = (bf16*)(ws + (49u << 20));        // 8 MB
  bf16*  kpk   = xb;                               // packed sorted K (xb dead after GEMM)

  sort_lag_kernel<<<64, 256, 0, stream>>>(lag, perm, slag);
  prep_kernel<<<3084, 256, 0, stream>>>(x, wq, wk, wv, wo, bq, bk, bv,
                                        xb, wqkvt, wot, bqkv);
  gemm_bt_kernel<1><<<dim3(24, 32), 256, 0, stream>>>(
      xb, wqkvt, bqkv, qkv, 4096, 3072, 1024, 1024, 0.125f * 1.44269504f);
  pack_kv_kernel<<<1024, 256, 0, stream>>>(qkv, perm, kpk, vtb);
  attn_kernel<<<512, 256, 0, stream>>>(qkv, kpk, vtb, lag, slag, lag_bias, aout);
  gemm64_kernel<<<dim3(8, 64), 256, 0, stream>>>(
      aout, wot, bo, (float*)d_out, 4096, 1024, 1024);
}

// Round 15
// 159.599 us; speedup vs baseline: 2.0545x; 1.0132x over previous
//
#include <hip/hip_runtime.h>

typedef __bf16 bf16;
typedef __bf16 bf16x8 __attribute__((ext_vector_type(8)));
typedef float f32x4 __attribute__((ext_vector_type(4)));

__device__ __forceinline__ f32x4 mfma16(bf16x8 a, bf16x8 b, f32x4 c) {
  return __builtin_amdgcn_mfma_f32_16x16x32_bf16(a, b, c, 0, 0, 0);
}
__device__ __forceinline__ void gload16(const bf16* g, bf16* l) {
  __builtin_amdgcn_global_load_lds((const __attribute__((address_space(1))) unsigned int*)g,
                                   (__attribute__((address_space(3))) unsigned int*)l, 16, 0, 0);
}

// ------- fused prep: x f32->bf16 (blocks 0..2047), 4x weight transpose (2048..3071),
//         bias concat (3072..3083). grid 3084 -------
__global__ __launch_bounds__(256) void prep_kernel(
    const float* __restrict__ x, const float* __restrict__ wq,
    const float* __restrict__ wk, const float* __restrict__ wv,
    const float* __restrict__ wo, const float* __restrict__ bq,
    const float* __restrict__ bk, const float* __restrict__ bv,
    bf16* __restrict__ xb, bf16* __restrict__ wqkvt, bf16* __restrict__ wot,
    float* __restrict__ bqkv) {
  int blk = blockIdx.x;
  int tid = threadIdx.x;
  if (blk < 2048) {
    int i = blk * 256 + tid;
    const float4* p = (const float4*)x + (size_t)i * 2;
    float4 f0 = p[0], f1 = p[1];
    bf16x8 o;
    o[0] = (bf16)f0.x; o[1] = (bf16)f0.y; o[2] = (bf16)f0.z; o[3] = (bf16)f0.w;
    o[4] = (bf16)f1.x; o[5] = (bf16)f1.y; o[6] = (bf16)f1.z; o[7] = (bf16)f1.w;
    *((bf16x8*)xb + i) = o;
    return;
  }
  if (blk >= 3072) {
    int i = (blk - 3072) * 256 + tid;
    if (i < 1024) bqkv[i] = bq[i];
    else if (i < 2048) bqkv[i] = bk[i - 1024];
    else if (i < 3072) bqkv[i] = bv[i - 2048];
    return;
  }
  __shared__ float t[64][68];
  int sub = blk - 2048;
  int wsel = sub >> 8;
  sub &= 255;
  const float* in = wsel == 0 ? wq : wsel == 1 ? wk : wsel == 2 ? wv : wo;
  bf16* out = (wsel == 3) ? wot : (wqkvt + (size_t)wsel * (1u << 20));
  int bx = sub & 15;
  int by = sub >> 4;
  int r = tid >> 2, p = tid & 3;
  const float* src = in + (size_t)(by * 64 + r) * 1024 + bx * 64 + p * 16;
#pragma unroll
  for (int j = 0; j < 16; j += 4)
    *(float4*)&t[r][p * 16 + j] = *(const float4*)(src + j);
  __syncthreads();
  int n = tid >> 2, sp = tid & 3;
  bf16 tmp[16];
#pragma unroll
  for (int j = 0; j < 16; ++j) tmp[j] = (bf16)t[sp * 16 + j][n];
  bf16* dst = out + (size_t)(bx * 64 + n) * 1024 + by * 64 + sp * 16;
  *(bf16x8*)dst = *(bf16x8*)&tmp[0];
  *(bf16x8*)(dst + 8) = *(bf16x8*)&tmp[8];
}

// ---------------- parallel deterministic stable sort of lag by rank ----------------
__global__ __launch_bounds__(256) void sort_lag_kernel(const int* __restrict__ lag,
                                                       int* __restrict__ perm,
                                                       int* __restrict__ slag) {
  __shared__ int l[2048];
  int tid = threadIdx.x;
  for (int i = tid; i < 2048; i += 256) l[i] = lag[i];
  __syncthreads();
  int i = blockIdx.x * 32 + (tid >> 3);
  int s = tid & 7;
  int vi = l[i];
  int cnt = 0;
  for (int j = s * 256; j < s * 256 + 256; j += 4) {
    int4 vj = *(const int4*)&l[j];
    cnt += (vj.x < vi || (vj.x == vi && (j + 0) < i));
    cnt += (vj.y < vi || (vj.y == vi && (j + 1) < i));
    cnt += (vj.z < vi || (vj.z == vi && (j + 2) < i));
    cnt += (vj.w < vi || (vj.w == vi && (j + 3) < i));
  }
  cnt += __shfl_xor(cnt, 1);
  cnt += __shfl_xor(cnt, 2);
  cnt += __shfl_xor(cnt, 4);
  if (s == 0) { perm[cnt] = i; slag[cnt] = vi; }
}

// ---- pack K rows sorted (kp[(b*16+h)*2048+ss][64]) + V transpose sorted (vt[bh][d][ss]) ----
__global__ __launch_bounds__(256) void pack_kv_kernel(const bf16* __restrict__ qkv,
                                                      const int* __restrict__ perm,
                                                      bf16* __restrict__ kp,
                                                      bf16* __restrict__ vt) {
  __shared__ bf16 t[64][72];
  int blk = blockIdx.x;
  int st = blk & 31, h = (blk >> 5) & 15, b = blk >> 9;
  int tid = threadIdx.x;
  int r = tid >> 2, p = tid & 3;
  int src_s = perm[st * 64 + r];
  {
    const bf16* src = qkv + (size_t)(b * 2048 + src_s) * 3072 + 1024 + h * 64 + p * 16;
    bf16* dst = kp + (size_t)((b * 16 + h) * 2048 + st * 64 + r) * 64 + p * 16;
    *(bf16x8*)dst = *(const bf16x8*)src;
    *(bf16x8*)(dst + 8) = *(const bf16x8*)(src + 8);
  }
  {
    const bf16* src = qkv + (size_t)(b * 2048 + src_s) * 3072 + 2048 + h * 64 + p * 16;
    *(bf16x8*)&t[r][p * 16] = *(const bf16x8*)src;
    *(bf16x8*)&t[r][p * 16 + 8] = *(const bf16x8*)(src + 8);
    __syncthreads();
    int d = tid >> 2, sp = tid & 3;
    bf16 tmp[16];
#pragma unroll
    for (int j = 0; j < 16; ++j) tmp[j] = t[sp * 16 + j][d];
    bf16* dst = vt + (size_t)((b * 16 + h) * 64 + d) * 2048 + st * 64 + sp * 16;
    *(bf16x8*)dst = *(bf16x8*)&tmp[0];
    *(bf16x8*)(dst + 8) = *(bf16x8*)&tmp[8];
  }
}

// ---------------- bf16 GEMM 128x128 (QKV projection): C = A * Bt^T + bias, col-scale ----------------
template <int OUT_BF16>
__global__ __launch_bounds__(256) void gemm_bt_kernel(
    const bf16* __restrict__ A, const bf16* __restrict__ Bt,
    const float* __restrict__ bias, void* __restrict__ C,
    int M, int N, int K, int scale_cols, float scale_val) {
  __shared__ __align__(16) bf16 As[128 * 64];
  __shared__ __align__(16) bf16 Bs[128 * 64];
  int bn = blockIdx.x * 128, bm = blockIdx.y * 128;
  int tid = threadIdx.x;
  int l = tid & 63;
  int w = tid >> 6;
  int wr = w >> 1, wc = w & 1;
  int g = l >> 4, c = l & 15;
  int swz = (c & 7) << 3;
  int srow = l >> 3;
  int scol = ((l & 7) ^ srow) << 3;
  const bf16* Ap = A + (size_t)(bm + w * 32 + srow) * K + scol;
  const bf16* Bp = Bt + (size_t)(bn + w * 32 + srow) * K + scol;
  bf16* AsW = As + w * 32 * 64;
  bf16* BsW = Bs + w * 32 * 64;

  f32x4 acc[4][4] = {};
  for (int k0 = 0; k0 < K; k0 += 64) {
    __syncthreads();
#pragma unroll
    for (int i = 0; i < 4; ++i) {
      gload16(Ap + (size_t)(8 * i) * K + k0, AsW + i * 512);
      gload16(Bp + (size_t)(8 * i) * K + k0, BsW + i * 512);
    }
    __syncthreads();
#pragma unroll
    for (int kh = 0; kh < 2; ++kh) {
      bf16x8 af[4], bfr[4];
#pragma unroll
      for (int m = 0; m < 4; ++m)
        af[m] = *(const bf16x8*)&As[(wr * 64 + m * 16 + c) * 64 + ((kh * 32 + g * 8) ^ swz)];
#pragma unroll
      for (int n = 0; n < 4; ++n)
        bfr[n] = *(const bf16x8*)&Bs[(wc * 64 + n * 16 + c) * 64 + ((kh * 32 + g * 8) ^ swz)];
#pragma unroll
      for (int m = 0; m < 4; ++m)
#pragma unroll
        for (int n = 0; n < 4; ++n)
          acc[m][n] = mfma16(af[m], bfr[n], acc[m][n]);
    }
  }
  int rowb = bm + wr * 64;
  int colb = bn + wc * 64;
#pragma unroll
  for (int n = 0; n < 4; ++n) {
    int col = colb + n * 16 + c;
    float bv = bias[col];
    float s = (col < scale_cols) ? scale_val : 1.0f;
#pragma unroll
    for (int m = 0; m < 4; ++m) {
      int row = rowb + m * 16 + g * 4;
#pragma unroll
      for (int j = 0; j < 4; ++j) {
        float v = (acc[m][n][j] + bv) * s;
        if (OUT_BF16)
          ((bf16*)C)[(size_t)(row + j) * N + col] = (bf16)v;
        else
          ((float*)C)[(size_t)(row + j) * N + col] = v;
      }
    }
  }
}

// ---------------- bf16 GEMM 64x128 tile (out-projection): grid (N/128, M/64) ----------------
__global__ __launch_bounds__(256) void gemm64_kernel(
    const bf16* __restrict__ A, const bf16* __restrict__ Bt,
    const float* __restrict__ bias, float* __restrict__ C,
    int M, int N, int K) {
  __shared__ __align__(16) bf16 As[64 * 64];
  __shared__ __align__(16) bf16 Bs[128 * 64];
  int bn = blockIdx.x * 128, bm = blockIdx.y * 64;
  int tid = threadIdx.x;
  int l = tid & 63;
  int w = tid >> 6;
  int g = l >> 4, c = l & 15;
  int swz = (c & 7) << 3;
  int srow = l >> 3;
  int scol = ((l & 7) ^ srow) << 3;
  const bf16* Ap = A + (size_t)(bm + w * 16 + srow) * K + scol;
  const bf16* Bp = Bt + (size_t)(bn + w * 32 + srow) * K + scol;
  bf16* AsW = As + w * 16 * 64;
  bf16* BsW = Bs + w * 32 * 64;

  f32x4 acc[4][2] = {};
  for (int k0 = 0; k0 < K; k0 += 64) {
    __syncthreads();
#pragma unroll
    for (int i = 0; i < 2; ++i)
      gload16(Ap + (size_t)(8 * i) * K + k0, AsW + i * 512);
#pragma unroll
    for (int i = 0; i < 4; ++i)
      gload16(Bp + (size_t)(8 * i) * K + k0, BsW + i * 512);
    __syncthreads();
#pragma unroll
    for (int kh = 0; kh < 2; ++kh) {
      int koff = (kh * 32 + g * 8) ^ swz;
      bf16x8 af[4], bfr[2];
#pragma unroll
      for (int m = 0; m < 4; ++m)
        af[m] = *(const bf16x8*)&As[(m * 16 + c) * 64 + koff];
#pragma unroll
      for (int n = 0; n < 2; ++n)
        bfr[n] = *(const bf16x8*)&Bs[(w * 32 + n * 16 + c) * 64 + koff];
#pragma unroll
      for (int m = 0; m < 4; ++m)
#pragma unroll
        for (int n = 0; n < 2; ++n)
          acc[m][n] = mfma16(af[m], bfr[n], acc[m][n]);
    }
  }
#pragma unroll
  for (int n = 0; n < 2; ++n) {
    int col = bn + w * 32 + n * 16 + c;
    float bv = bias[col];
#pragma unroll
    for (int m = 0; m < 4; ++m) {
      int row = bm + m * 16 + g * 4;
#pragma unroll
      for (int j = 0; j < 4; ++j)
        C[(size_t)(row + j) * N + col] = acc[m][n][j] + bv;
    }
  }
}

// ---------------- flash attention (sorted keys, 32 q/wave, mirrored bias, MFMA-ones psum) ----------------
// R14-validated config. New: row-sum computed by mfma16(pa, ONES) into psacc — removes the
// 32 per-tile psum VALU adds and the entire epilogue shfl reduction. psacc[m][j] holds
// sum_k P[q=m*16+g*4+j][k] replicated across c-lanes (C/D col = B-idx), same verified layout.
__global__ __launch_bounds__(256) void attn_kernel(
    const bf16* __restrict__ qkv, const bf16* __restrict__ kp,
    const bf16* __restrict__ vt, const int* __restrict__ lag,
    const int* __restrict__ slag, const float* __restrict__ lag_bias,
    bf16* __restrict__ out) {
  __shared__ __align__(16) bf16 Ks0[64 * 64];
  __shared__ __align__(16) bf16 Vs0[64 * 64];
  __shared__ __align__(16) bf16 Ks1[64 * 64];
  __shared__ __align__(16) bf16 Vs1[64 * 64];
  __shared__ __align__(16) bf16 Ps[4][32][72];
  __shared__ float bias2_s[1028];
  __shared__ int lag_s[2048];   // sorted lag (keys)

  int blk = blockIdx.x;
  blk = (blk & 7) * 64 + (blk >> 3);  // bijective XCD swizzle (512 % 8 == 0)
  int qt = blk & 15;
  int h = (blk >> 4) & 15;
  int b = blk >> 8;
  int tid = threadIdx.x;
  int w = tid >> 6, l = tid & 63, g = l >> 4, c = l & 15;

  for (int i = tid; i < 1025; i += 256) {
    int d = i - 512;
    d = d < 0 ? -d : d;
    bias2_s[i] = lag_bias[h * 513 + d] * 1.44269504f;
  }
  for (int i = tid; i < 2048; i += 256) lag_s[i] = slag[i];

  int q0 = qt * 128 + w * 32;
  const bf16* qbase = qkv + (size_t)(b * 2048 + q0) * 3072 + h * 64;
  bf16x8 qf[2][2];
#pragma unroll
  for (int m = 0; m < 2; ++m)
#pragma unroll
    for (int kh = 0; kh < 2; ++kh)
      qf[m][kh] = *(const bf16x8*)(qbase + (size_t)(m * 16 + c) * 3072 + kh * 32 + g * 8);

  int lagq[2][4];
#pragma unroll
  for (int m = 0; m < 2; ++m)
#pragma unroll
    for (int j = 0; j < 4; ++j) lagq[m][j] = lag[q0 + m * 16 + g * 4 + j] + 512;

  // all-ones B-fragment for the row-sum MFMA
  bf16x8 ones8;
#pragma unroll
  for (int e = 0; e < 8; ++e) ones8[e] = (bf16)1.0f;

  // fragment-read column offsets (XOR-swizzled LDS layout)
  int swz = (c & 7) << 3;
  int off0 = (g * 8) ^ swz;
  int off1 = off0 ^ 32;

  // staging: thread covers 16B; wave w owns rows w*16..w*16+15 (two 8-row chunks)
  int r0 = w * 16 + (l >> 3);
  int colE = ((l & 7) ^ (l >> 3)) << 3;  // inverse-swizzled global column
  const bf16* kbase = kp + (size_t)(b * 16 + h) * 2048 * 64;
  const bf16* vbase = vt + (size_t)(b * 16 + h) * 64 * 2048;
  const bf16* kg0 = kbase + (size_t)r0 * 64 + colE;
  const bf16* kg1 = kbase + (size_t)(r0 + 8) * 64 + colE;
  const bf16* vg0 = vbase + (size_t)r0 * 2048 + colE;
  const bf16* vg1 = vbase + (size_t)(r0 + 8) * 2048 + colE;

#define STAGE(KD, VD)                    \
  do {                                   \
    gload16(kg0, KD + w * 1024);         \
    gload16(kg1, KD + w * 1024 + 512);   \
    gload16(vg0, VD + w * 1024);         \
    gload16(vg1, VD + w * 1024 + 512);   \
    kg0 += 64 * 64; kg1 += 64 * 64;      \
    vg0 += 64; vg1 += 64;                \
  } while (0)

  STAGE(Ks0, Vs0);
  __syncthreads();

  f32x4 oacc[2][4] = {};
  f32x4 psacc[2] = {};

#define TILE(KB, VB, KT)                                                          \
  do {                                                                            \
    f32x4 sf[2][4] = {};                                                          \
    int lagk[4];                                                                  \
    _Pragma("unroll") for (int kb = 0; kb < 4; ++kb) {                            \
      int row = kb * 16 + c;                                                      \
      bf16x8 k0 = *(const bf16x8*)&KB[row * 64 + off0];                           \
      bf16x8 k1 = *(const bf16x8*)&KB[row * 64 + off1];                           \
      sf[0][kb] = mfma16(qf[0][0], k0, sf[0][kb]);                                \
      sf[0][kb] = mfma16(qf[0][1], k1, sf[0][kb]);                                \
      sf[1][kb] = mfma16(qf[1][0], k0, sf[1][kb]);                                \
      sf[1][kb] = mfma16(qf[1][1], k1, sf[1][kb]);                                \
      lagk[kb] = lag_s[(KT) + kb * 16 + c];                                       \
    }                                                                             \
    _Pragma("unroll") for (int m = 0; m < 2; ++m)                                 \
    _Pragma("unroll") for (int kb = 0; kb < 4; ++kb)                              \
    _Pragma("unroll") for (int j = 0; j < 4; ++j) {                               \
      int ld = lagq[m][j] - lagk[kb];                                             \
      float p = __builtin_amdgcn_exp2f(sf[m][kb][j] + bias2_s[ld]);               \
      Ps[w][m * 16 + g * 4 + j][kb * 16 + c] = (bf16)p;                           \
    }                                                                             \
    asm volatile("s_waitcnt lgkmcnt(0)" ::: "memory");                            \
    _Pragma("unroll") for (int ph = 0; ph < 2; ++ph) {                            \
      bf16x8 pa0 = *(const bf16x8*)&Ps[w][c][ph * 32 + g * 8];                    \
      bf16x8 pa1 = *(const bf16x8*)&Ps[w][16 + c][ph * 32 + g * 8];               \
      int voff = ph ? off1 : off0;                                                \
      _Pragma("unroll") for (int n = 0; n < 4; ++n) {                             \
        bf16x8 vf = *(const bf16x8*)&VB[(n * 16 + c) * 64 + voff];                \
        oacc[0][n] = mfma16(pa0, vf, oacc[0][n]);                                 \
        oacc[1][n] = mfma16(pa1, vf, oacc[1][n]);                                 \
      }                                                                           \
      psacc[0] = mfma16(pa0, ones8, psacc[0]);                                    \
      psacc[1] = mfma16(pa1, ones8, psacc[1]);                                    \
    }                                                                             \
  } while (0)

  for (int kt = 0; kt < 2048; kt += 128) {
    if (kt + 64 < 2048) STAGE(Ks1, Vs1);
    TILE(Ks0, Vs0, kt);
    __syncthreads();  // drains vmcnt: Ks1/Vs1 ready; closes Ks0/Vs0 reads
    if (kt + 128 < 2048) STAGE(Ks0, Vs0);
    TILE(Ks1, Vs1, kt + 64);
    __syncthreads();
  }

  // normalize + store (psacc already holds the full row sums, replicated over c-lanes)
#pragma unroll
  for (int m = 0; m < 2; ++m) {
#pragma unroll
    for (int j = 0; j < 4; ++j) {
      float inv = 1.f / psacc[m][j];
      bf16* ob = out + (size_t)(b * 2048 + q0 + m * 16 + g * 4 + j) * 1024 + h * 64;
#pragma unroll
      for (int n = 0; n < 4; ++n)
        ob[n * 16 + c] = (bf16)(oacc[m][n][j] * inv);
    }
  }
#undef STAGE
#undef TILE
}

extern "C" void kernel_launch(void* const* d_in, const int* in_sizes, int n_in,
                              void* d_out, int out_size, void* d_ws, size_t ws_size,
                              hipStream_t stream) {
  const float* x        = (const float*)d_in[0];
  const int*   lag      = (const int*)d_in[1];
  const float* wq       = (const float*)d_in[2];
  const float* bq       = (const float*)d_in[3];
  const float* wk       = (const float*)d_in[4];
  const float* bk       = (const float*)d_in[5];
  const float* wv       = (const float*)d_in[6];
  const float* bv       = (const float*)d_in[7];
  const float* wo       = (const float*)d_in[8];
  const float* bo       = (const float*)d_in[9];
  const float* lag_bias = (const float*)d_in[10];

  char* ws = (char*)d_ws;
  bf16*  xb    = (bf16*)ws;                        // 8 MB (x bf16; reused as kp after QKV GEMM)
  bf16*  wqkvt = (bf16*)(ws + (8u  << 20));        // 6 MB
  bf16*  wot   = (bf16*)(ws + (14u << 20));        // 2 MB
  float* bqkv  = (float*)(ws + (16u << 20));       // 12 KB
  int*   perm  = (int*)(ws + (16u << 20) + 32768); // 8 KB
  int*   slag  = (int*)(ws + (16u << 20) + 65536); // 8 KB
  bf16*  qkv   = (bf16*)(ws + (17u << 20));        // 24 MB
  bf16*  vtb   = (bf16*)(ws + (41u << 20));        // 8 MB
  bf16*  aout  = (bf16*)(ws + (49u << 20));        // 8 MB
  bf16*  kpk   = xb;                               // packed sorted K (xb dead after GEMM)

  sort_lag_kernel<<<64, 256, 0, stream>>>(lag, perm, slag);
  prep_kernel<<<3084, 256, 0, stream>>>(x, wq, wk, wv, wo, bq, bk, bv,
                                        xb, wqkvt, wot, bqkv);
  gemm_bt_kernel<1><<<dim3(24, 32), 256, 0, stream>>>(
      xb, wqkvt, bqkv, qkv, 4096, 3072, 1024, 1024, 0.125f * 1.44269504f);
  pack_kv_kernel<<<1024, 256, 0, stream>>>(qkv, perm, kpk, vtb);
  attn_kernel<<<512, 256, 0, stream>>>(qkv, kpk, vtb, lag, slag, lag_bias, aout);
  gemm64_kernel<<<dim3(8, 64), 256, 0, stream>>>(
      aout, wot, bo, (float*)d_out, 4096, 1024, 1024);
}